// Round 1
// baseline (899.806 us; speedup 1.0000x reference)
//
#include <hip/hip_runtime.h>
#include <stdint.h>
#include <math.h>

#define NTOK  8192
#define DIM   1024
#define HID   2048
#define NE    8

#define BK    64
#define LDK   72   // padded LDS row stride (bf16 units); 144 B = 9*16 -> 16B-aligned, breaks pow2 bank stride

typedef __attribute__((ext_vector_type(8))) short short8;
typedef __attribute__((ext_vector_type(4))) float f32x4;

__device__ __forceinline__ unsigned short f2bf(float f) {
  union { float f; unsigned u; } a; a.f = f;
  unsigned u = a.u;
  u += 0x7fffu + ((u >> 16) & 1u);   // RNE
  return (unsigned short)(u >> 16);
}

__global__ void zero_out_kernel(float4* p, int n4) {
  int i = blockIdx.x * blockDim.x + threadIdx.x;
  if (i < n4) p[i] = make_float4(0.f, 0.f, 0.f, 0.f);
}

__global__ void zero_cnt_kernel(int* cnt) {
  if (threadIdx.x < NE) cnt[threadIdx.x] = 0;
}

__global__ void cast_x_kernel(const float* __restrict__ x, unsigned short* __restrict__ xb) {
  int i = blockIdx.x * blockDim.x + threadIdx.x;  // one per 4 floats; grid covers exactly NTOK*DIM/4
  float4 v = ((const float4*)x)[i];
  ushort4 o;
  o.x = f2bf(v.x); o.y = f2bf(v.y); o.z = f2bf(v.z); o.w = f2bf(v.w);
  ((ushort4*)xb)[i] = o;
}

// in: fp32 [E][R][C]  ->  out: bf16 [E][C][R]
__global__ void transpose_cast_kernel(const float* __restrict__ in, unsigned short* __restrict__ out,
                                      int R, int C) {
  __shared__ float tile[32][33];
  int e = blockIdx.z;
  const float* ine = in + (size_t)e * R * C;
  unsigned short* oute = out + (size_t)e * R * C;
  int tx = threadIdx.x, ty = threadIdx.y;
  int c = blockIdx.x * 32 + tx;
  #pragma unroll
  for (int i = 0; i < 32; i += 8) {
    int r = blockIdx.y * 32 + ty + i;
    tile[ty + i][tx] = ine[(size_t)r * C + c];
  }
  __syncthreads();
  int cc = blockIdx.y * 32 + tx;
  #pragma unroll
  for (int i = 0; i < 32; i += 8) {
    int rr = blockIdx.x * 32 + ty + i;
    oute[(size_t)rr * R + cc] = f2bf(tile[tx][ty + i]);
  }
}

// one wave per token: gate = x @ Wg, top-2 + softmax, append to per-expert lists
__global__ __launch_bounds__(256) void gate_route_kernel(
    const float* __restrict__ x, const float* __restrict__ Wg,
    int* __restrict__ cnt, int* __restrict__ tok_list, float* __restrict__ prob_list) {
  int wid = threadIdx.x >> 6;
  int lane = threadIdx.x & 63;
  int t = blockIdx.x * 4 + wid;
  const float* xr = x + (size_t)t * DIM;
  float acc[NE];
  #pragma unroll
  for (int e = 0; e < NE; e++) acc[e] = 0.f;
  for (int d = lane; d < DIM; d += 64) {
    float xv = xr[d];
    const float* wr = Wg + d * NE;
    #pragma unroll
    for (int e = 0; e < NE; e++) acc[e] += xv * wr[e];
  }
  #pragma unroll
  for (int e = 0; e < NE; e++) {
    float v = acc[e];
    #pragma unroll
    for (int off = 32; off > 0; off >>= 1) v += __shfl_xor(v, off);
    acc[e] = v;
  }
  if (lane == 0) {
    int i0 = 0; float v0 = acc[0];
    #pragma unroll
    for (int e = 1; e < NE; e++) if (acc[e] > v0) { v0 = acc[e]; i0 = e; }
    int i1 = -1; float v1 = -3.4e38f;
    #pragma unroll
    for (int e = 0; e < NE; e++) if (e != i0 && acc[e] > v1) { v1 = acc[e]; i1 = e; }
    float e1 = expf(v1 - v0);
    float p0 = 1.f / (1.f + e1);
    float p1 = e1 / (1.f + e1);
    int s0 = atomicAdd(&cnt[i0], 1);
    tok_list[i0 * NTOK + s0] = t;
    prob_list[i0 * NTOK + s0] = p0;
    int s1 = atomicAdd(&cnt[i1], 1);
    tok_list[i1 * NTOK + s1] = t;
    prob_list[i1 * NTOK + s1] = p1;
  }
}

__global__ void prefix_kernel(const int* __restrict__ cnt, int* __restrict__ base) {
  if (threadIdx.x == 0) {
    int s = 0;
    for (int e = 0; e < NE; e++) { base[e] = s; s += cnt[e]; }
  }
}

// grouped dual GEMM: a = A@W1t^T, v = A@W2t^T over gathered token rows; h = swish(a)*v -> hbuf (bf16)
// tile: M=128 (tokens), N=64 (per each of W1/W2), K-step 64. 4 waves, each 64x32 per GEMM (4x2 frags x2).
__global__ __launch_bounds__(256, 2) void gemm1_kernel(
    const unsigned short* __restrict__ xb,
    const unsigned short* __restrict__ w1t,
    const unsigned short* __restrict__ w2t,
    const int* __restrict__ cnt, const int* __restrict__ base,
    const int* __restrict__ tok_list,
    unsigned short* __restrict__ hbuf) {
  int e = blockIdx.z;
  int count = cnt[e];
  int mt = blockIdx.y;
  if (mt * 128 >= count) return;
  int nt = blockIdx.x;

  __shared__ __align__(16) unsigned short As[128 * LDK];
  __shared__ __align__(16) unsigned short Bs1[64 * LDK];
  __shared__ __align__(16) unsigned short Bs2[64 * LDK];
  __shared__ int toks[128];

  int tid = threadIdx.x;
  if (tid < 128) {
    int r = mt * 128 + tid;
    toks[tid] = tok_list[e * NTOK + (r < count ? r : 0)];
  }
  __syncthreads();

  const unsigned short* W1e = w1t + (size_t)e * HID * DIM + (size_t)(nt * 64) * DIM;
  const unsigned short* W2e = w2t + (size_t)e * HID * DIM + (size_t)(nt * 64) * DIM;

  f32x4 acc1[4][2], acc2[4][2];
  f32x4 zz = {0.f, 0.f, 0.f, 0.f};
  #pragma unroll
  for (int i = 0; i < 4; i++)
    #pragma unroll
    for (int j = 0; j < 2; j++) { acc1[i][j] = zz; acc2[i][j] = zz; }

  int wid = tid >> 6, lane = tid & 63;
  int wm = wid >> 1, wn = wid & 1;
  int m16 = lane & 15, quad = lane >> 4;

  for (int k0 = 0; k0 < DIM; k0 += BK) {
    #pragma unroll
    for (int i = 0; i < 4; i++) {              // A: 128 rows x 8 chunks of 8 bf16
      int s = tid + 256 * i;
      int row = s >> 3, ch = s & 7;
      *(uint4*)(As + row * LDK + ch * 8) =
          *(const uint4*)(xb + (size_t)toks[row] * DIM + k0 + ch * 8);
    }
    #pragma unroll
    for (int i = 0; i < 2; i++) {              // B1,B2: 64 rows x 8 chunks
      int s = tid + 256 * i;
      int row = s >> 3, ch = s & 7;
      *(uint4*)(Bs1 + row * LDK + ch * 8) =
          *(const uint4*)(W1e + (size_t)row * DIM + k0 + ch * 8);
      *(uint4*)(Bs2 + row * LDK + ch * 8) =
          *(const uint4*)(W2e + (size_t)row * DIM + k0 + ch * 8);
    }
    __syncthreads();
    #pragma unroll
    for (int ks = 0; ks < 2; ks++) {
      int ko = ks * 32 + quad * 8;
      short8 af[4], b1f[2], b2f[2];
      #pragma unroll
      for (int fm = 0; fm < 4; fm++)
        af[fm] = *(const short8*)(As + (wm * 64 + fm * 16 + m16) * LDK + ko);
      #pragma unroll
      for (int fn = 0; fn < 2; fn++) {
        b1f[fn] = *(const short8*)(Bs1 + (wn * 32 + fn * 16 + m16) * LDK + ko);
        b2f[fn] = *(const short8*)(Bs2 + (wn * 32 + fn * 16 + m16) * LDK + ko);
      }
      #pragma unroll
      for (int fm = 0; fm < 4; fm++)
        #pragma unroll
        for (int fn = 0; fn < 2; fn++) {
          acc1[fm][fn] = __builtin_amdgcn_mfma_f32_16x16x32_bf16(af[fm], b1f[fn], acc1[fm][fn], 0, 0, 0);
          acc2[fm][fn] = __builtin_amdgcn_mfma_f32_16x16x32_bf16(af[fm], b2f[fn], acc2[fm][fn], 0, 0, 0);
        }
    }
    __syncthreads();
  }

  int hb = base[e];
  #pragma unroll
  for (int fm = 0; fm < 4; fm++)
    #pragma unroll
    for (int fn = 0; fn < 2; fn++)
      #pragma unroll
      for (int r = 0; r < 4; r++) {
        int row = wm * 64 + fm * 16 + quad * 4 + r;   // C/D: col=lane&15, row=quad*4+reg
        if (mt * 128 + row < count) {
          float a = acc1[fm][fn][r];
          float v = acc2[fm][fn][r];
          float h = (a / (1.f + __expf(-a))) * v;
          int col = nt * 64 + wn * 32 + fn * 16 + m16;
          hbuf[(size_t)(hb + mt * 128 + row) * HID + col] = f2bf(h);
        }
      }
}

// y = hbuf @ W3t^T, scatter out[tok] += prob * y. tile 128x128, K-step 64. 4 waves, each 64x64 (4x4 frags).
__global__ __launch_bounds__(256, 2) void gemm2_kernel(
    const unsigned short* __restrict__ hbuf,
    const unsigned short* __restrict__ w3t,
    const int* __restrict__ cnt, const int* __restrict__ base,
    const int* __restrict__ tok_list, const float* __restrict__ prob_list,
    float* __restrict__ out) {
  int e = blockIdx.z;
  int count = cnt[e];
  int mt = blockIdx.y;
  if (mt * 128 >= count) return;
  int nt = blockIdx.x;

  __shared__ __align__(16) unsigned short As[128 * LDK];
  __shared__ __align__(16) unsigned short Bs[128 * LDK];
  __shared__ int toks[128];
  __shared__ float probs[128];

  int tid = threadIdx.x;
  int hb = base[e];
  if (tid < 128) {
    int r = mt * 128 + tid;
    int rc = (r < count) ? r : 0;
    toks[tid] = tok_list[e * NTOK + rc];
    probs[tid] = prob_list[e * NTOK + rc];
  }
  __syncthreads();

  const unsigned short* W3e = w3t + (size_t)e * DIM * HID + (size_t)(nt * 128) * HID;

  f32x4 acc[4][4];
  f32x4 zz = {0.f, 0.f, 0.f, 0.f};
  #pragma unroll
  for (int i = 0; i < 4; i++)
    #pragma unroll
    for (int j = 0; j < 4; j++) acc[i][j] = zz;

  int wid = tid >> 6, lane = tid & 63;
  int wm = wid >> 1, wn = wid & 1;
  int m16 = lane & 15, quad = lane >> 4;

  for (int k0 = 0; k0 < HID; k0 += BK) {
    #pragma unroll
    for (int i = 0; i < 4; i++) {
      int s = tid + 256 * i;
      int row = s >> 3, ch = s & 7;
      int r = mt * 128 + row;
      int rc = (r < count) ? r : mt * 128;   // clamp to a valid row of this expert
      *(uint4*)(As + row * LDK + ch * 8) =
          *(const uint4*)(hbuf + (size_t)(hb + rc) * HID + k0 + ch * 8);
      *(uint4*)(Bs + row * LDK + ch * 8) =
          *(const uint4*)(W3e + (size_t)row * HID + k0 + ch * 8);
    }
    __syncthreads();
    #pragma unroll
    for (int ks = 0; ks < 2; ks++) {
      int ko = ks * 32 + quad * 8;
      short8 af[4], bf[4];
      #pragma unroll
      for (int fm = 0; fm < 4; fm++)
        af[fm] = *(const short8*)(As + (wm * 64 + fm * 16 + m16) * LDK + ko);
      #pragma unroll
      for (int fn = 0; fn < 4; fn++)
        bf[fn] = *(const short8*)(Bs + (wn * 64 + fn * 16 + m16) * LDK + ko);
      #pragma unroll
      for (int fm = 0; fm < 4; fm++)
        #pragma unroll
        for (int fn = 0; fn < 4; fn++)
          acc[fm][fn] = __builtin_amdgcn_mfma_f32_16x16x32_bf16(af[fm], bf[fn], acc[fm][fn], 0, 0, 0);
    }
    __syncthreads();
  }

  #pragma unroll
  for (int fm = 0; fm < 4; fm++)
    #pragma unroll
    for (int fn = 0; fn < 4; fn++)
      #pragma unroll
      for (int r = 0; r < 4; r++) {
        int row = wm * 64 + fm * 16 + quad * 4 + r;
        if (mt * 128 + row < count) {
          int tok = toks[row];
          float p = probs[row];
          int col = nt * 128 + wn * 64 + fn * 16 + m16;
          atomicAdd(&out[(size_t)tok * DIM + col], p * acc[fm][fn][r]);
        }
      }
}

extern "C" void kernel_launch(void* const* d_in, const int* in_sizes, int n_in,
                              void* d_out, int out_size, void* d_ws, size_t ws_size,
                              hipStream_t stream) {
  const float* x  = (const float*)d_in[0];
  const float* Wg = (const float*)d_in[1];
  const float* W1 = (const float*)d_in[2];
  const float* W2 = (const float*)d_in[3];
  const float* W3 = (const float*)d_in[4];
  float* out = (float*)d_out;

  // workspace layout (~185.1 MB total)
  char* ws = (char*)d_ws;
  size_t off = 0;
  int* cnt = (int*)(ws + off); off += 256;
  int* base = (int*)(ws + off); off += 256;
  int* tok_list = (int*)(ws + off); off += (size_t)NE * NTOK * 4;
  float* prob_list = (float*)(ws + off); off += (size_t)NE * NTOK * 4;
  unsigned short* xb  = (unsigned short*)(ws + off); off += (size_t)NTOK * DIM * 2;
  unsigned short* w1t = (unsigned short*)(ws + off); off += (size_t)NE * DIM * HID * 2;
  unsigned short* w2t = (unsigned short*)(ws + off); off += (size_t)NE * DIM * HID * 2;
  unsigned short* w3t = (unsigned short*)(ws + off); off += (size_t)NE * DIM * HID * 2;
  unsigned short* hbuf = (unsigned short*)(ws + off); off += (size_t)NTOK * 2 * HID * 2;

  zero_cnt_kernel<<<1, 64, 0, stream>>>(cnt);
  zero_out_kernel<<<(NTOK * DIM / 4 + 255) / 256, 256, 0, stream>>>((float4*)out, NTOK * DIM / 4);
  cast_x_kernel<<<NTOK * DIM / 4 / 256, 256, 0, stream>>>(x, xb);
  transpose_cast_kernel<<<dim3(HID / 32, DIM / 32, NE), dim3(32, 8), 0, stream>>>(W1, w1t, DIM, HID);
  transpose_cast_kernel<<<dim3(HID / 32, DIM / 32, NE), dim3(32, 8), 0, stream>>>(W2, w2t, DIM, HID);
  transpose_cast_kernel<<<dim3(DIM / 32, HID / 32, NE), dim3(32, 8), 0, stream>>>(W3, w3t, HID, DIM);
  gate_route_kernel<<<NTOK / 4, 256, 0, stream>>>(x, Wg, cnt, tok_list, prob_list);
  prefix_kernel<<<1, 1, 0, stream>>>(cnt, base);
  gemm1_kernel<<<dim3(HID / 64, NTOK / 128, NE), 256, 0, stream>>>(xb, w1t, w2t, cnt, base, tok_list, hbuf);
  gemm2_kernel<<<dim3(DIM / 128, NTOK / 128, NE), 256, 0, stream>>>(hbuf, w3t, cnt, base, tok_list, prob_list, out);
}

// Round 2
// 732.955 us; speedup vs baseline: 1.2276x; 1.2276x over previous
//
#include <hip/hip_runtime.h>
#include <stdint.h>
#include <math.h>

#define NTOK  8192
#define DIM   1024
#define HID   2048
#define NE    8

typedef __attribute__((ext_vector_type(8))) short short8;
typedef __attribute__((ext_vector_type(4))) float f32x4;

__device__ __forceinline__ unsigned short f2bf(float f) {
  union { float f; unsigned u; } a; a.f = f;
  unsigned u = a.u;
  u += 0x7fffu + ((u >> 16) & 1u);   // RNE
  return (unsigned short)(u >> 16);
}

// async global->LDS, 16B per lane. lds dest = wave-uniform base + lane*16.
__device__ __forceinline__ void gl2lds16(const unsigned short* g, unsigned short* l) {
  __builtin_amdgcn_global_load_lds(
      (const __attribute__((address_space(1))) unsigned int*)g,
      (__attribute__((address_space(3))) unsigned int*)l,
      16, 0, 0);
}

__global__ void zero_out_kernel(float4* p, int n4) {
  int i = blockIdx.x * blockDim.x + threadIdx.x;
  if (i < n4) p[i] = make_float4(0.f, 0.f, 0.f, 0.f);
}

__global__ void zero_cnt_kernel(int* cnt) {
  if (threadIdx.x < NE) cnt[threadIdx.x] = 0;
}

__global__ void cast_x_kernel(const float* __restrict__ x, unsigned short* __restrict__ xb) {
  int i = blockIdx.x * blockDim.x + threadIdx.x;
  float4 v = ((const float4*)x)[i];
  ushort4 o;
  o.x = f2bf(v.x); o.y = f2bf(v.y); o.z = f2bf(v.z); o.w = f2bf(v.w);
  ((ushort4*)xb)[i] = o;
}

// in: fp32 [E][R][C]  ->  out: bf16 [E][C][R]
__global__ void transpose_cast_kernel(const float* __restrict__ in, unsigned short* __restrict__ out,
                                      int R, int C) {
  __shared__ float tile[32][33];
  int e = blockIdx.z;
  const float* ine = in + (size_t)e * R * C;
  unsigned short* oute = out + (size_t)e * R * C;
  int tx = threadIdx.x, ty = threadIdx.y;
  int c = blockIdx.x * 32 + tx;
  #pragma unroll
  for (int i = 0; i < 32; i += 8) {
    int r = blockIdx.y * 32 + ty + i;
    tile[ty + i][tx] = ine[(size_t)r * C + c];
  }
  __syncthreads();
  int cc = blockIdx.y * 32 + tx;
  #pragma unroll
  for (int i = 0; i < 32; i += 8) {
    int rr = blockIdx.x * 32 + ty + i;
    oute[(size_t)rr * R + cc] = f2bf(tile[tx][ty + i]);
  }
}

// one wave per token: gate = x @ Wg, top-2 + softmax, append to per-expert lists
__global__ __launch_bounds__(256) void gate_route_kernel(
    const float* __restrict__ x, const float* __restrict__ Wg,
    int* __restrict__ cnt, int* __restrict__ tok_list, float* __restrict__ prob_list) {
  int wid = threadIdx.x >> 6;
  int lane = threadIdx.x & 63;
  int t = blockIdx.x * 4 + wid;
  const float* xr = x + (size_t)t * DIM;
  float acc[NE];
  #pragma unroll
  for (int e = 0; e < NE; e++) acc[e] = 0.f;
  for (int d = lane; d < DIM; d += 64) {
    float xv = xr[d];
    const float* wr = Wg + d * NE;
    #pragma unroll
    for (int e = 0; e < NE; e++) acc[e] += xv * wr[e];
  }
  #pragma unroll
  for (int e = 0; e < NE; e++) {
    float v = acc[e];
    #pragma unroll
    for (int off = 32; off > 0; off >>= 1) v += __shfl_xor(v, off);
    acc[e] = v;
  }
  if (lane == 0) {
    int i0 = 0; float v0 = acc[0];
    #pragma unroll
    for (int e = 1; e < NE; e++) if (acc[e] > v0) { v0 = acc[e]; i0 = e; }
    int i1 = -1; float v1 = -3.4e38f;
    #pragma unroll
    for (int e = 0; e < NE; e++) if (e != i0 && acc[e] > v1) { v1 = acc[e]; i1 = e; }
    float e1 = expf(v1 - v0);
    float p0 = 1.f / (1.f + e1);
    float p1 = e1 / (1.f + e1);
    int s0 = atomicAdd(&cnt[i0], 1);
    tok_list[i0 * NTOK + s0] = t;
    prob_list[i0 * NTOK + s0] = p0;
    int s1 = atomicAdd(&cnt[i1], 1);
    tok_list[i1 * NTOK + s1] = t;
    prob_list[i1 * NTOK + s1] = p1;
  }
}

__global__ void prefix_kernel(const int* __restrict__ cnt, int* __restrict__ base) {
  if (threadIdx.x == 0) {
    int s = 0;
    for (int e = 0; e < NE; e++) { base[e] = s; s += cnt[e]; }
  }
}

// grouped dual GEMM: a = A@W1t^T, v = A@W2t^T; h = swish(a)*v -> hbuf (bf16)
// tile M=128 x N=64(x2), K-step 64. XOR-swizzled LDS (16B chunks), async staging.
__global__ __launch_bounds__(256, 3) void gemm1_kernel(
    const unsigned short* __restrict__ xb,
    const unsigned short* __restrict__ w1t,
    const unsigned short* __restrict__ w2t,
    const int* __restrict__ cnt, const int* __restrict__ base,
    const int* __restrict__ tok_list,
    unsigned short* __restrict__ hbuf) {
  int e = blockIdx.z;
  int count = cnt[e];
  int mt = blockIdx.y;
  if (mt * 128 >= count) return;
  int nt = blockIdx.x;

  __shared__ __align__(16) unsigned short As[128 * 64];
  __shared__ __align__(16) unsigned short Bs1[64 * 64];
  __shared__ __align__(16) unsigned short Bs2[64 * 64];
  __shared__ int toks[128];

  int tid = threadIdx.x;
  if (tid < 128) {
    int r = mt * 128 + tid;
    toks[tid] = tok_list[e * NTOK + (r < count ? r : 0)];
  }
  __syncthreads();

  int wid = tid >> 6, lane = tid & 63;
  int wm = wid >> 1, wn = wid & 1;
  int m16 = lane & 15, quad = lane >> 4;

  const unsigned short* W1e = w1t + (size_t)e * HID * DIM + (size_t)(nt * 64) * DIM;
  const unsigned short* W2e = w2t + (size_t)e * HID * DIM + (size_t)(nt * 64) * DIM;

  // staging source pointers (swizzled chunk g = c ^ (r&7)), hoisted out of K loop
  const unsigned short* aptr[4];
  #pragma unroll
  for (int i = 0; i < 4; i++) {
    int slot = wid * 256 + i * 64 + lane;
    int r = slot >> 3, c = slot & 7, g = c ^ (r & 7);
    aptr[i] = xb + (size_t)toks[r] * DIM + g * 8;
  }
  const unsigned short *b1p[2], *b2p[2];
  #pragma unroll
  for (int i = 0; i < 2; i++) {
    int slot = wid * 128 + i * 64 + lane;
    int r = slot >> 3, c = slot & 7, g = c ^ (r & 7);
    b1p[i] = W1e + (size_t)r * DIM + g * 8;
    b2p[i] = W2e + (size_t)r * DIM + g * 8;
  }

  f32x4 acc1[4][2], acc2[4][2];
  f32x4 zz = {0.f, 0.f, 0.f, 0.f};
  #pragma unroll
  for (int i = 0; i < 4; i++)
    #pragma unroll
    for (int j = 0; j < 2; j++) { acc1[i][j] = zz; acc2[i][j] = zz; }

  for (int k0 = 0; k0 < DIM; k0 += 64) {
    #pragma unroll
    for (int i = 0; i < 4; i++)
      gl2lds16(aptr[i] + k0, As + (wid * 256 + i * 64) * 8);
    #pragma unroll
    for (int i = 0; i < 2; i++) {
      gl2lds16(b1p[i] + k0, Bs1 + (wid * 128 + i * 64) * 8);
      gl2lds16(b2p[i] + k0, Bs2 + (wid * 128 + i * 64) * 8);
    }
    __syncthreads();
    #pragma unroll
    for (int ks = 0; ks < 2; ks++) {
      int ga = ks * 4 + quad;
      short8 af[4], b1f[2], b2f[2];
      #pragma unroll
      for (int fm = 0; fm < 4; fm++) {
        int ra = wm * 64 + fm * 16 + m16;
        af[fm] = *(const short8*)(As + ra * 64 + (ga ^ (ra & 7)) * 8);
      }
      #pragma unroll
      for (int fn = 0; fn < 2; fn++) {
        int rb = wn * 32 + fn * 16 + m16;
        b1f[fn] = *(const short8*)(Bs1 + rb * 64 + (ga ^ (rb & 7)) * 8);
        b2f[fn] = *(const short8*)(Bs2 + rb * 64 + (ga ^ (rb & 7)) * 8);
      }
      #pragma unroll
      for (int fm = 0; fm < 4; fm++)
        #pragma unroll
        for (int fn = 0; fn < 2; fn++) {
          acc1[fm][fn] = __builtin_amdgcn_mfma_f32_16x16x32_bf16(af[fm], b1f[fn], acc1[fm][fn], 0, 0, 0);
          acc2[fm][fn] = __builtin_amdgcn_mfma_f32_16x16x32_bf16(af[fm], b2f[fn], acc2[fm][fn], 0, 0, 0);
        }
    }
    __syncthreads();
  }

  int hb = base[e];
  #pragma unroll
  for (int fm = 0; fm < 4; fm++)
    #pragma unroll
    for (int fn = 0; fn < 2; fn++)
      #pragma unroll
      for (int r = 0; r < 4; r++) {
        int row = wm * 64 + fm * 16 + quad * 4 + r;   // C/D: col=lane&15, row=quad*4+reg
        if (mt * 128 + row < count) {
          float a = acc1[fm][fn][r];
          float v = acc2[fm][fn][r];
          float h = (a / (1.f + __expf(-a))) * v;
          int col = nt * 64 + wn * 32 + fn * 16 + m16;
          hbuf[(size_t)(hb + mt * 128 + row) * HID + col] = f2bf(h);
        }
      }
}

// y = hbuf @ W3t^T, scatter out[tok] += prob * y. tile 128x128, K-step 64.
__global__ __launch_bounds__(256, 3) void gemm2_kernel(
    const unsigned short* __restrict__ hbuf,
    const unsigned short* __restrict__ w3t,
    const int* __restrict__ cnt, const int* __restrict__ base,
    const int* __restrict__ tok_list, const float* __restrict__ prob_list,
    float* __restrict__ out) {
  int e = blockIdx.z;
  int count = cnt[e];
  int mt = blockIdx.y;
  if (mt * 128 >= count) return;
  int nt = blockIdx.x;

  __shared__ __align__(16) unsigned short As[128 * 64];
  __shared__ __align__(16) unsigned short Bs[128 * 64];
  __shared__ int toks[128];
  __shared__ float probs[128];

  int tid = threadIdx.x;
  int hb = base[e];
  if (tid < 128) {
    int r = mt * 128 + tid;
    int rc = (r < count) ? r : 0;
    toks[tid] = tok_list[e * NTOK + rc];
    probs[tid] = prob_list[e * NTOK + rc];
  }
  __syncthreads();

  int wid = tid >> 6, lane = tid & 63;
  int wm = wid >> 1, wn = wid & 1;
  int m16 = lane & 15, quad = lane >> 4;

  const unsigned short* W3e = w3t + (size_t)e * DIM * HID + (size_t)(nt * 128) * HID;

  const unsigned short *aptr[4], *bptr[4];
  #pragma unroll
  for (int i = 0; i < 4; i++) {
    int slot = wid * 256 + i * 64 + lane;
    int r = slot >> 3, c = slot & 7, g = c ^ (r & 7);
    int gr = mt * 128 + r;
    int rc = (gr < count) ? gr : (count - 1);
    aptr[i] = hbuf + (size_t)(hb + rc) * HID + g * 8;
    bptr[i] = W3e + (size_t)r * HID + g * 8;
  }

  f32x4 acc[4][4];
  f32x4 zz = {0.f, 0.f, 0.f, 0.f};
  #pragma unroll
  for (int i = 0; i < 4; i++)
    #pragma unroll
    for (int j = 0; j < 4; j++) acc[i][j] = zz;

  for (int k0 = 0; k0 < HID; k0 += 64) {
    #pragma unroll
    for (int i = 0; i < 4; i++) {
      gl2lds16(aptr[i] + k0, As + (wid * 256 + i * 64) * 8);
      gl2lds16(bptr[i] + k0, Bs + (wid * 256 + i * 64) * 8);
    }
    __syncthreads();
    #pragma unroll
    for (int ks = 0; ks < 2; ks++) {
      int ga = ks * 4 + quad;
      short8 af[4], bf[4];
      #pragma unroll
      for (int fm = 0; fm < 4; fm++) {
        int ra = wm * 64 + fm * 16 + m16;
        af[fm] = *(const short8*)(As + ra * 64 + (ga ^ (ra & 7)) * 8);
      }
      #pragma unroll
      for (int fn = 0; fn < 4; fn++) {
        int rb = wn * 64 + fn * 16 + m16;
        bf[fn] = *(const short8*)(Bs + rb * 64 + (ga ^ (rb & 7)) * 8);
      }
      #pragma unroll
      for (int fm = 0; fm < 4; fm++)
        #pragma unroll
        for (int fn = 0; fn < 4; fn++)
          acc[fm][fn] = __builtin_amdgcn_mfma_f32_16x16x32_bf16(af[fm], bf[fn], acc[fm][fn], 0, 0, 0);
    }
    __syncthreads();
  }

  #pragma unroll
  for (int fm = 0; fm < 4; fm++)
    #pragma unroll
    for (int fn = 0; fn < 4; fn++)
      #pragma unroll
      for (int r = 0; r < 4; r++) {
        int row = wm * 64 + fm * 16 + quad * 4 + r;
        if (mt * 128 + row < count) {
          int tok = toks[row];
          float p = probs[row];
          int col = nt * 128 + wn * 64 + fn * 16 + m16;
          atomicAdd(&out[(size_t)tok * DIM + col], p * acc[fm][fn][r]);
        }
      }
}

extern "C" void kernel_launch(void* const* d_in, const int* in_sizes, int n_in,
                              void* d_out, int out_size, void* d_ws, size_t ws_size,
                              hipStream_t stream) {
  const float* x  = (const float*)d_in[0];
  const float* Wg = (const float*)d_in[1];
  const float* W1 = (const float*)d_in[2];
  const float* W2 = (const float*)d_in[3];
  const float* W3 = (const float*)d_in[4];
  float* out = (float*)d_out;

  // workspace layout (~185.1 MB total)
  char* ws = (char*)d_ws;
  size_t off = 0;
  int* cnt = (int*)(ws + off); off += 256;
  int* base = (int*)(ws + off); off += 256;
  int* tok_list = (int*)(ws + off); off += (size_t)NE * NTOK * 4;
  float* prob_list = (float*)(ws + off); off += (size_t)NE * NTOK * 4;
  unsigned short* xb  = (unsigned short*)(ws + off); off += (size_t)NTOK * DIM * 2;
  unsigned short* w1t = (unsigned short*)(ws + off); off += (size_t)NE * DIM * HID * 2;
  unsigned short* w2t = (unsigned short*)(ws + off); off += (size_t)NE * DIM * HID * 2;
  unsigned short* w3t = (unsigned short*)(ws + off); off += (size_t)NE * DIM * HID * 2;
  unsigned short* hbuf = (unsigned short*)(ws + off); off += (size_t)NTOK * 2 * HID * 2;

  zero_cnt_kernel<<<1, 64, 0, stream>>>(cnt);
  zero_out_kernel<<<(NTOK * DIM / 4 + 255) / 256, 256, 0, stream>>>((float4*)out, NTOK * DIM / 4);
  cast_x_kernel<<<NTOK * DIM / 4 / 256, 256, 0, stream>>>(x, xb);
  transpose_cast_kernel<<<dim3(HID / 32, DIM / 32, NE), dim3(32, 8), 0, stream>>>(W1, w1t, DIM, HID);
  transpose_cast_kernel<<<dim3(HID / 32, DIM / 32, NE), dim3(32, 8), 0, stream>>>(W2, w2t, DIM, HID);
  transpose_cast_kernel<<<dim3(DIM / 32, HID / 32, NE), dim3(32, 8), 0, stream>>>(W3, w3t, HID, DIM);
  gate_route_kernel<<<NTOK / 4, 256, 0, stream>>>(x, Wg, cnt, tok_list, prob_list);
  prefix_kernel<<<1, 1, 0, stream>>>(cnt, base);
  gemm1_kernel<<<dim3(HID / 64, NTOK / 128, NE), 256, 0, stream>>>(xb, w1t, w2t, cnt, base, tok_list, hbuf);
  gemm2_kernel<<<dim3(DIM / 128, NTOK / 128, NE), 256, 0, stream>>>(hbuf, w3t, cnt, base, tok_list, prob_list, out);
}

// Round 3
// 554.674 us; speedup vs baseline: 1.6222x; 1.3214x over previous
//
#include <hip/hip_runtime.h>
#include <stdint.h>
#include <math.h>

#define NTOK  8192
#define DIM   1024
#define HID   2048
#define NE    8

typedef __attribute__((ext_vector_type(8))) short short8;
typedef __attribute__((ext_vector_type(4))) float f32x4;

__device__ __forceinline__ unsigned short f2bf(float f) {
  union { float f; unsigned u; } a; a.f = f;
  unsigned u = a.u;
  u += 0x7fffu + ((u >> 16) & 1u);   // RNE
  return (unsigned short)(u >> 16);
}

// async global->LDS, 16B per lane. lds dest = wave-uniform base + lane*16.
__device__ __forceinline__ void gl2lds16(const unsigned short* g, unsigned short* l) {
  __builtin_amdgcn_global_load_lds(
      (const __attribute__((address_space(1))) unsigned int*)g,
      (__attribute__((address_space(3))) unsigned int*)l,
      16, 0, 0);
}

__global__ void zero_out_kernel(float4* p, int n4) {
  int i = blockIdx.x * blockDim.x + threadIdx.x;
  if (i < n4) p[i] = make_float4(0.f, 0.f, 0.f, 0.f);
}

__global__ void zero_cnt_kernel(int* cnt) {
  if (threadIdx.x < NE) cnt[threadIdx.x] = 0;
}

// in: fp32 [E][R][C]  ->  out: bf16 [E][C][R]
__global__ void transpose_cast_kernel(const float* __restrict__ in, unsigned short* __restrict__ out,
                                      int R, int C) {
  __shared__ float tile[32][33];
  int e = blockIdx.z;
  const float* ine = in + (size_t)e * R * C;
  unsigned short* oute = out + (size_t)e * R * C;
  int tx = threadIdx.x, ty = threadIdx.y;
  int c = blockIdx.x * 32 + tx;
  #pragma unroll
  for (int i = 0; i < 32; i += 8) {
    int r = blockIdx.y * 32 + ty + i;
    tile[ty + i][tx] = ine[(size_t)r * C + c];
  }
  __syncthreads();
  int cc = blockIdx.y * 32 + tx;
  #pragma unroll
  for (int i = 0; i < 32; i += 8) {
    int rr = blockIdx.x * 32 + ty + i;
    oute[(size_t)rr * R + cc] = f2bf(tile[tx][ty + i]);
  }
}

// one wave per token: gate = x @ Wg, top-2 + softmax -> packed idx + probs.
// No global atomics. Also fuses x -> bf16 cast (same read of x).
__global__ __launch_bounds__(256) void gate_kernel(
    const float* __restrict__ x, const float* __restrict__ Wg,
    unsigned short* __restrict__ xb,
    int* __restrict__ eidx, float* __restrict__ eprob) {
  int wid = threadIdx.x >> 6;
  int lane = threadIdx.x & 63;
  int t = blockIdx.x * 4 + wid;
  const float* xr = x + (size_t)t * DIM;
  unsigned short* xbr = xb + (size_t)t * DIM;
  float acc[NE];
  #pragma unroll
  for (int e = 0; e < NE; e++) acc[e] = 0.f;
  #pragma unroll
  for (int it = 0; it < DIM / 64; it++) {
    int d = it * 64 + lane;
    float xv = xr[d];
    xbr[d] = f2bf(xv);
    const float4* wr = (const float4*)(Wg + d * NE);
    float4 w0 = wr[0], w1 = wr[1];
    acc[0] += xv * w0.x; acc[1] += xv * w0.y; acc[2] += xv * w0.z; acc[3] += xv * w0.w;
    acc[4] += xv * w1.x; acc[5] += xv * w1.y; acc[6] += xv * w1.z; acc[7] += xv * w1.w;
  }
  #pragma unroll
  for (int e = 0; e < NE; e++) {
    float v = acc[e];
    #pragma unroll
    for (int off = 32; off > 0; off >>= 1) v += __shfl_xor(v, off);
    acc[e] = v;
  }
  if (lane == 0) {
    int i0 = 0; float v0 = acc[0];
    #pragma unroll
    for (int e = 1; e < NE; e++) if (acc[e] > v0) { v0 = acc[e]; i0 = e; }
    int i1 = -1; float v1 = -3.4e38f;
    #pragma unroll
    for (int e = 0; e < NE; e++) if (e != i0 && acc[e] > v1) { v1 = acc[e]; i1 = e; }
    float e1 = expf(v1 - v0);
    float p0 = 1.f / (1.f + e1);
    float p1 = e1 / (1.f + e1);
    eidx[t] = i0 | (i1 << 16);
    eprob[2 * t] = p0;
    eprob[2 * t + 1] = p1;
  }
}

// per-block LDS histogram, one global atomic per (block, expert), then scatter.
__global__ __launch_bounds__(512) void route_kernel(
    const int* __restrict__ eidx, const float* __restrict__ eprob,
    int* __restrict__ cnt, int* __restrict__ tok_list, float* __restrict__ prob_list) {
  __shared__ int lhist[NE];
  __shared__ int gbase[NE];
  int tid = threadIdx.x;
  if (tid < NE) lhist[tid] = 0;
  __syncthreads();
  int t = blockIdx.x * 512 + tid;
  int pk = eidx[t];
  int i0 = pk & 0xffff, i1 = pk >> 16;
  int l0 = atomicAdd(&lhist[i0], 1);
  int l1 = atomicAdd(&lhist[i1], 1);
  __syncthreads();
  if (tid < NE) gbase[tid] = atomicAdd(&cnt[tid], lhist[tid]);
  __syncthreads();
  int s0 = gbase[i0] + l0;
  tok_list[i0 * NTOK + s0] = t;
  prob_list[i0 * NTOK + s0] = eprob[2 * t];
  int s1 = gbase[i1] + l1;
  tok_list[i1 * NTOK + s1] = t;
  prob_list[i1 * NTOK + s1] = eprob[2 * t + 1];
}

__global__ void prefix_kernel(const int* __restrict__ cnt, int* __restrict__ base) {
  if (threadIdx.x == 0) {
    int s = 0;
    for (int e = 0; e < NE; e++) { base[e] = s; s += cnt[e]; }
  }
}

// grouped dual GEMM: a = A@W1t^T, v = A@W2t^T; h = swish(a)*v -> hbuf (bf16)
// tile M=128 x N=64(x2), K-step 64. XOR-swizzled LDS (16B chunks), async staging.
__global__ __launch_bounds__(256, 3) void gemm1_kernel(
    const unsigned short* __restrict__ xb,
    const unsigned short* __restrict__ w1t,
    const unsigned short* __restrict__ w2t,
    const int* __restrict__ cnt, const int* __restrict__ base,
    const int* __restrict__ tok_list,
    unsigned short* __restrict__ hbuf) {
  int e = blockIdx.z;
  int count = cnt[e];
  int mt = blockIdx.y;
  if (mt * 128 >= count) return;
  int nt = blockIdx.x;

  __shared__ __align__(16) unsigned short As[128 * 64];
  __shared__ __align__(16) unsigned short Bs1[64 * 64];
  __shared__ __align__(16) unsigned short Bs2[64 * 64];
  __shared__ int toks[128];

  int tid = threadIdx.x;
  if (tid < 128) {
    int r = mt * 128 + tid;
    toks[tid] = tok_list[e * NTOK + (r < count ? r : 0)];
  }
  __syncthreads();

  int wid = tid >> 6, lane = tid & 63;
  int wm = wid >> 1, wn = wid & 1;
  int m16 = lane & 15, quad = lane >> 4;

  const unsigned short* W1e = w1t + (size_t)e * HID * DIM + (size_t)(nt * 64) * DIM;
  const unsigned short* W2e = w2t + (size_t)e * HID * DIM + (size_t)(nt * 64) * DIM;

  const unsigned short* aptr[4];
  #pragma unroll
  for (int i = 0; i < 4; i++) {
    int slot = wid * 256 + i * 64 + lane;
    int r = slot >> 3, c = slot & 7, g = c ^ (r & 7);
    aptr[i] = xb + (size_t)toks[r] * DIM + g * 8;
  }
  const unsigned short *b1p[2], *b2p[2];
  #pragma unroll
  for (int i = 0; i < 2; i++) {
    int slot = wid * 128 + i * 64 + lane;
    int r = slot >> 3, c = slot & 7, g = c ^ (r & 7);
    b1p[i] = W1e + (size_t)r * DIM + g * 8;
    b2p[i] = W2e + (size_t)r * DIM + g * 8;
  }

  f32x4 acc1[4][2], acc2[4][2];
  f32x4 zz = {0.f, 0.f, 0.f, 0.f};
  #pragma unroll
  for (int i = 0; i < 4; i++)
    #pragma unroll
    for (int j = 0; j < 2; j++) { acc1[i][j] = zz; acc2[i][j] = zz; }

  for (int k0 = 0; k0 < DIM; k0 += 64) {
    #pragma unroll
    for (int i = 0; i < 4; i++)
      gl2lds16(aptr[i] + k0, As + (wid * 256 + i * 64) * 8);
    #pragma unroll
    for (int i = 0; i < 2; i++) {
      gl2lds16(b1p[i] + k0, Bs1 + (wid * 128 + i * 64) * 8);
      gl2lds16(b2p[i] + k0, Bs2 + (wid * 128 + i * 64) * 8);
    }
    __syncthreads();
    #pragma unroll
    for (int ks = 0; ks < 2; ks++) {
      int ga = ks * 4 + quad;
      short8 af[4], b1f[2], b2f[2];
      #pragma unroll
      for (int fm = 0; fm < 4; fm++) {
        int ra = wm * 64 + fm * 16 + m16;
        af[fm] = *(const short8*)(As + ra * 64 + (ga ^ (ra & 7)) * 8);
      }
      #pragma unroll
      for (int fn = 0; fn < 2; fn++) {
        int rb = wn * 32 + fn * 16 + m16;
        b1f[fn] = *(const short8*)(Bs1 + rb * 64 + (ga ^ (rb & 7)) * 8);
        b2f[fn] = *(const short8*)(Bs2 + rb * 64 + (ga ^ (rb & 7)) * 8);
      }
      #pragma unroll
      for (int fm = 0; fm < 4; fm++)
        #pragma unroll
        for (int fn = 0; fn < 2; fn++) {
          acc1[fm][fn] = __builtin_amdgcn_mfma_f32_16x16x32_bf16(af[fm], b1f[fn], acc1[fm][fn], 0, 0, 0);
          acc2[fm][fn] = __builtin_amdgcn_mfma_f32_16x16x32_bf16(af[fm], b2f[fn], acc2[fm][fn], 0, 0, 0);
        }
    }
    __syncthreads();
  }

  int hb = base[e];
  #pragma unroll
  for (int fm = 0; fm < 4; fm++)
    #pragma unroll
    for (int fn = 0; fn < 2; fn++)
      #pragma unroll
      for (int r = 0; r < 4; r++) {
        int row = wm * 64 + fm * 16 + quad * 4 + r;   // C/D: col=lane&15, row=quad*4+reg
        if (mt * 128 + row < count) {
          float a = acc1[fm][fn][r];
          float v = acc2[fm][fn][r];
          float h = (a / (1.f + __expf(-a))) * v;
          int col = nt * 64 + wn * 32 + fn * 16 + m16;
          hbuf[(size_t)(hb + mt * 128 + row) * HID + col] = f2bf(h);
        }
      }
}

// y = hbuf @ W3t^T, scatter out[tok] += prob * y. tile 128x128, K-step 64.
__global__ __launch_bounds__(256, 3) void gemm2_kernel(
    const unsigned short* __restrict__ hbuf,
    const unsigned short* __restrict__ w3t,
    const int* __restrict__ cnt, const int* __restrict__ base,
    const int* __restrict__ tok_list, const float* __restrict__ prob_list,
    float* __restrict__ out) {
  int e = blockIdx.z;
  int count = cnt[e];
  int mt = blockIdx.y;
  if (mt * 128 >= count) return;
  int nt = blockIdx.x;

  __shared__ __align__(16) unsigned short As[128 * 64];
  __shared__ __align__(16) unsigned short Bs[128 * 64];
  __shared__ int toks[128];
  __shared__ float probs[128];

  int tid = threadIdx.x;
  int hb = base[e];
  if (tid < 128) {
    int r = mt * 128 + tid;
    int rc = (r < count) ? r : 0;
    toks[tid] = tok_list[e * NTOK + rc];
    probs[tid] = prob_list[e * NTOK + rc];
  }
  __syncthreads();

  int wid = tid >> 6, lane = tid & 63;
  int wm = wid >> 1, wn = wid & 1;
  int m16 = lane & 15, quad = lane >> 4;

  const unsigned short* W3e = w3t + (size_t)e * DIM * HID + (size_t)(nt * 128) * HID;

  const unsigned short *aptr[4], *bptr[4];
  #pragma unroll
  for (int i = 0; i < 4; i++) {
    int slot = wid * 256 + i * 64 + lane;
    int r = slot >> 3, c = slot & 7, g = c ^ (r & 7);
    int gr = mt * 128 + r;
    int rc = (gr < count) ? gr : (count - 1);
    aptr[i] = hbuf + (size_t)(hb + rc) * HID + g * 8;
    bptr[i] = W3e + (size_t)r * HID + g * 8;
  }

  f32x4 acc[4][4];
  f32x4 zz = {0.f, 0.f, 0.f, 0.f};
  #pragma unroll
  for (int i = 0; i < 4; i++)
    #pragma unroll
    for (int j = 0; j < 4; j++) acc[i][j] = zz;

  for (int k0 = 0; k0 < HID; k0 += 64) {
    #pragma unroll
    for (int i = 0; i < 4; i++) {
      gl2lds16(aptr[i] + k0, As + (wid * 256 + i * 64) * 8);
      gl2lds16(bptr[i] + k0, Bs + (wid * 256 + i * 64) * 8);
    }
    __syncthreads();
    #pragma unroll
    for (int ks = 0; ks < 2; ks++) {
      int ga = ks * 4 + quad;
      short8 af[4], bf[4];
      #pragma unroll
      for (int fm = 0; fm < 4; fm++) {
        int ra = wm * 64 + fm * 16 + m16;
        af[fm] = *(const short8*)(As + ra * 64 + (ga ^ (ra & 7)) * 8);
      }
      #pragma unroll
      for (int fn = 0; fn < 4; fn++) {
        int rb = wn * 64 + fn * 16 + m16;
        bf[fn] = *(const short8*)(Bs + rb * 64 + (ga ^ (rb & 7)) * 8);
      }
      #pragma unroll
      for (int fm = 0; fm < 4; fm++)
        #pragma unroll
        for (int fn = 0; fn < 4; fn++)
          acc[fm][fn] = __builtin_amdgcn_mfma_f32_16x16x32_bf16(af[fm], bf[fn], acc[fm][fn], 0, 0, 0);
    }
    __syncthreads();
  }

  #pragma unroll
  for (int fm = 0; fm < 4; fm++)
    #pragma unroll
    for (int fn = 0; fn < 4; fn++)
      #pragma unroll
      for (int r = 0; r < 4; r++) {
        int row = wm * 64 + fm * 16 + quad * 4 + r;
        if (mt * 128 + row < count) {
          int tok = toks[row];
          float p = probs[row];
          int col = nt * 128 + wn * 64 + fn * 16 + m16;
          atomicAdd(&out[(size_t)tok * DIM + col], p * acc[fm][fn][r]);
        }
      }
}

extern "C" void kernel_launch(void* const* d_in, const int* in_sizes, int n_in,
                              void* d_out, int out_size, void* d_ws, size_t ws_size,
                              hipStream_t stream) {
  const float* x  = (const float*)d_in[0];
  const float* Wg = (const float*)d_in[1];
  const float* W1 = (const float*)d_in[2];
  const float* W2 = (const float*)d_in[3];
  const float* W3 = (const float*)d_in[4];
  float* out = (float*)d_out;

  // workspace layout (~185.2 MB total)
  char* ws = (char*)d_ws;
  size_t off = 0;
  int* cnt = (int*)(ws + off); off += 256;
  int* base = (int*)(ws + off); off += 256;
  int* eidx = (int*)(ws + off); off += (size_t)NTOK * 4;
  float* eprob = (float*)(ws + off); off += (size_t)NTOK * 2 * 4;
  int* tok_list = (int*)(ws + off); off += (size_t)NE * NTOK * 4;
  float* prob_list = (float*)(ws + off); off += (size_t)NE * NTOK * 4;
  unsigned short* xb  = (unsigned short*)(ws + off); off += (size_t)NTOK * DIM * 2;
  unsigned short* w1t = (unsigned short*)(ws + off); off += (size_t)NE * DIM * HID * 2;
  unsigned short* w2t = (unsigned short*)(ws + off); off += (size_t)NE * DIM * HID * 2;
  unsigned short* w3t = (unsigned short*)(ws + off); off += (size_t)NE * DIM * HID * 2;
  unsigned short* hbuf = (unsigned short*)(ws + off); off += (size_t)NTOK * 2 * HID * 2;

  zero_cnt_kernel<<<1, 64, 0, stream>>>(cnt);
  zero_out_kernel<<<(NTOK * DIM / 4 + 255) / 256, 256, 0, stream>>>((float4*)out, NTOK * DIM / 4);
  gate_kernel<<<NTOK / 4, 256, 0, stream>>>(x, Wg, xb, eidx, eprob);
  transpose_cast_kernel<<<dim3(HID / 32, DIM / 32, NE), dim3(32, 8), 0, stream>>>(W1, w1t, DIM, HID);
  transpose_cast_kernel<<<dim3(HID / 32, DIM / 32, NE), dim3(32, 8), 0, stream>>>(W2, w2t, DIM, HID);
  transpose_cast_kernel<<<dim3(DIM / 32, HID / 32, NE), dim3(32, 8), 0, stream>>>(W3, w3t, HID, DIM);
  route_kernel<<<NTOK / 512, 512, 0, stream>>>(eidx, eprob, cnt, tok_list, prob_list);
  prefix_kernel<<<1, 1, 0, stream>>>(cnt, base);
  gemm1_kernel<<<dim3(HID / 64, NTOK / 128, NE), 256, 0, stream>>>(xb, w1t, w2t, cnt, base, tok_list, hbuf);
  gemm2_kernel<<<dim3(DIM / 128, NTOK / 128, NE), 256, 0, stream>>>(hbuf, w3t, cnt, base, tok_list, prob_list, out);
}

// Round 4
// 527.157 us; speedup vs baseline: 1.7069x; 1.0522x over previous
//
#include <hip/hip_runtime.h>
#include <stdint.h>
#include <math.h>

#define NTOK  8192
#define DIM   1024
#define HID   2048
#define NE    8

typedef __attribute__((ext_vector_type(8))) short short8;
typedef __attribute__((ext_vector_type(4))) float f32x4;

__device__ __forceinline__ unsigned short f2bf(float f) {
  union { float f; unsigned u; } a; a.f = f;
  unsigned u = a.u;
  u += 0x7fffu + ((u >> 16) & 1u);   // RNE
  return (unsigned short)(u >> 16);
}

// async global->LDS, 16B per lane. lds dest = wave-uniform base + lane*16.
__device__ __forceinline__ void gl2lds16(const unsigned short* g, unsigned short* l) {
  __builtin_amdgcn_global_load_lds(
      (const __attribute__((address_space(1))) unsigned int*)g,
      (__attribute__((address_space(3))) unsigned int*)l,
      16, 0, 0);
}

// in: fp32 [E][R][C] -> out: bf16 [E][C][R].  64x64 tiles; coalesced float4
// loads, bf16 LDS tile, coalesced 16B stores.
__global__ __launch_bounds__(256) void transpose_cast_kernel(
    const float* __restrict__ in, unsigned short* __restrict__ out, int R, int C) {
  __shared__ unsigned short tileT[64][72];   // [c][r], +8 pad
  int e = blockIdx.z;
  const float* ine = in + (size_t)e * R * C + (size_t)(blockIdx.y * 64) * C + blockIdx.x * 64;
  unsigned short* oute = out + (size_t)e * R * C + (size_t)(blockIdx.x * 64) * R + blockIdx.y * 64;
  int t = threadIdx.x;
  #pragma unroll
  for (int i = 0; i < 4; i++) {
    int idx = t + i * 256;
    int r = idx >> 4, c = (idx & 15) * 4;
    float4 v = *(const float4*)(ine + (size_t)r * C + c);
    tileT[c + 0][r] = f2bf(v.x);
    tileT[c + 1][r] = f2bf(v.y);
    tileT[c + 2][r] = f2bf(v.z);
    tileT[c + 3][r] = f2bf(v.w);
  }
  __syncthreads();
  #pragma unroll
  for (int i = 0; i < 2; i++) {
    int idx = t + i * 256;
    int rr = idx >> 3, cc = (idx & 7) * 8;
    *(uint4*)(oute + (size_t)rr * R + cc) = *(const uint4*)(&tileT[rr][cc]);
  }
}

// one wave per token: gate = x @ Wg, top-2 + softmax -> packed idx + probs.
// Fuses x -> bf16 cast. Block 0 zeroes cnt (race-free: route runs after).
__global__ __launch_bounds__(256) void gate_kernel(
    const float* __restrict__ x, const float* __restrict__ Wg,
    unsigned short* __restrict__ xb,
    int* __restrict__ eidx, float* __restrict__ eprob, int* __restrict__ cnt) {
  if (blockIdx.x == 0 && threadIdx.x < NE) cnt[threadIdx.x] = 0;
  int wid = threadIdx.x >> 6;
  int lane = threadIdx.x & 63;
  int t = blockIdx.x * 4 + wid;
  const float* xr = x + (size_t)t * DIM;
  unsigned short* xbr = xb + (size_t)t * DIM;
  float acc[NE];
  #pragma unroll
  for (int e = 0; e < NE; e++) acc[e] = 0.f;
  #pragma unroll
  for (int it = 0; it < DIM / 64; it++) {
    int d = it * 64 + lane;
    float xv = xr[d];
    xbr[d] = f2bf(xv);
    const float4* wr = (const float4*)(Wg + d * NE);
    float4 w0 = wr[0], w1 = wr[1];
    acc[0] += xv * w0.x; acc[1] += xv * w0.y; acc[2] += xv * w0.z; acc[3] += xv * w0.w;
    acc[4] += xv * w1.x; acc[5] += xv * w1.y; acc[6] += xv * w1.z; acc[7] += xv * w1.w;
  }
  #pragma unroll
  for (int e = 0; e < NE; e++) {
    float v = acc[e];
    #pragma unroll
    for (int off = 32; off > 0; off >>= 1) v += __shfl_xor(v, off);
    acc[e] = v;
  }
  if (lane == 0) {
    int i0 = 0; float v0 = acc[0];
    #pragma unroll
    for (int e = 1; e < NE; e++) if (acc[e] > v0) { v0 = acc[e]; i0 = e; }
    int i1 = -1; float v1 = -3.4e38f;
    #pragma unroll
    for (int e = 0; e < NE; e++) if (e != i0 && acc[e] > v1) { v1 = acc[e]; i1 = e; }
    float e1 = expf(v1 - v0);
    float p0 = 1.f / (1.f + e1);
    float p1 = e1 / (1.f + e1);
    eidx[t] = i0 | (i1 << 16);
    eprob[2 * t] = p0;
    eprob[2 * t + 1] = p1;
  }
}

// per-block LDS histogram, one global atomic per (block, expert), then scatter.
// Also records each token's (expert, position) for the gather in combine.
__global__ __launch_bounds__(512) void route_kernel(
    const int* __restrict__ eidx,
    int* __restrict__ cnt, int* __restrict__ tok_list, int* __restrict__ slotpos) {
  __shared__ int lhist[NE];
  __shared__ int gbase[NE];
  int tid = threadIdx.x;
  if (tid < NE) lhist[tid] = 0;
  __syncthreads();
  int t = blockIdx.x * 512 + tid;
  int pk = eidx[t];
  int i0 = pk & 0xffff, i1 = pk >> 16;
  int l0 = atomicAdd(&lhist[i0], 1);
  int l1 = atomicAdd(&lhist[i1], 1);
  __syncthreads();
  if (tid < NE) gbase[tid] = atomicAdd(&cnt[tid], lhist[tid]);
  __syncthreads();
  int s0 = gbase[i0] + l0;
  int s1 = gbase[i1] + l1;
  tok_list[i0 * NTOK + s0] = t;
  tok_list[i1 * NTOK + s1] = t;
  slotpos[2 * t] = (i0 << 16) | s0;
  slotpos[2 * t + 1] = (i1 << 16) | s1;
}

// grouped dual GEMM: a = A@W1t^T, v = A@W2t^T; h = swish(a)*v -> hbuf (bf16)
// tile M=128 x N=64(x2), K-step 64. XOR-swizzled LDS (16B chunks), async staging.
__global__ __launch_bounds__(256, 3) void gemm1_kernel(
    const unsigned short* __restrict__ xb,
    const unsigned short* __restrict__ w1t,
    const unsigned short* __restrict__ w2t,
    const int* __restrict__ cnt,
    const int* __restrict__ tok_list,
    unsigned short* __restrict__ hbuf) {
  int e = blockIdx.z;
  int count = cnt[e];
  int mt = blockIdx.y;
  if (mt * 128 >= count) return;
  int nt = blockIdx.x;

  __shared__ __align__(16) unsigned short As[128 * 64];
  __shared__ __align__(16) unsigned short Bs1[64 * 64];
  __shared__ __align__(16) unsigned short Bs2[64 * 64];
  __shared__ int toks[128];

  int tid = threadIdx.x;
  if (tid < 128) {
    int r = mt * 128 + tid;
    toks[tid] = tok_list[e * NTOK + (r < count ? r : 0)];
  }
  __syncthreads();

  int wid = tid >> 6, lane = tid & 63;
  int wm = wid >> 1, wn = wid & 1;
  int m16 = lane & 15, quad = lane >> 4;

  const unsigned short* W1e = w1t + (size_t)e * HID * DIM + (size_t)(nt * 64) * DIM;
  const unsigned short* W2e = w2t + (size_t)e * HID * DIM + (size_t)(nt * 64) * DIM;

  const unsigned short* aptr[4];
  #pragma unroll
  for (int i = 0; i < 4; i++) {
    int slot = wid * 256 + i * 64 + lane;
    int r = slot >> 3, c = slot & 7, g = c ^ (r & 7);
    aptr[i] = xb + (size_t)toks[r] * DIM + g * 8;
  }
  const unsigned short *b1p[2], *b2p[2];
  #pragma unroll
  for (int i = 0; i < 2; i++) {
    int slot = wid * 128 + i * 64 + lane;
    int r = slot >> 3, c = slot & 7, g = c ^ (r & 7);
    b1p[i] = W1e + (size_t)r * DIM + g * 8;
    b2p[i] = W2e + (size_t)r * DIM + g * 8;
  }

  f32x4 acc1[4][2], acc2[4][2];
  f32x4 zz = {0.f, 0.f, 0.f, 0.f};
  #pragma unroll
  for (int i = 0; i < 4; i++)
    #pragma unroll
    for (int j = 0; j < 2; j++) { acc1[i][j] = zz; acc2[i][j] = zz; }

  for (int k0 = 0; k0 < DIM; k0 += 64) {
    #pragma unroll
    for (int i = 0; i < 4; i++)
      gl2lds16(aptr[i] + k0, As + (wid * 256 + i * 64) * 8);
    #pragma unroll
    for (int i = 0; i < 2; i++) {
      gl2lds16(b1p[i] + k0, Bs1 + (wid * 128 + i * 64) * 8);
      gl2lds16(b2p[i] + k0, Bs2 + (wid * 128 + i * 64) * 8);
    }
    __syncthreads();
    #pragma unroll
    for (int ks = 0; ks < 2; ks++) {
      int ga = ks * 4 + quad;
      short8 af[4], b1f[2], b2f[2];
      #pragma unroll
      for (int fm = 0; fm < 4; fm++) {
        int ra = wm * 64 + fm * 16 + m16;
        af[fm] = *(const short8*)(As + ra * 64 + (ga ^ (ra & 7)) * 8);
      }
      #pragma unroll
      for (int fn = 0; fn < 2; fn++) {
        int rb = wn * 32 + fn * 16 + m16;
        b1f[fn] = *(const short8*)(Bs1 + rb * 64 + (ga ^ (rb & 7)) * 8);
        b2f[fn] = *(const short8*)(Bs2 + rb * 64 + (ga ^ (rb & 7)) * 8);
      }
      #pragma unroll
      for (int fm = 0; fm < 4; fm++)
        #pragma unroll
        for (int fn = 0; fn < 2; fn++) {
          acc1[fm][fn] = __builtin_amdgcn_mfma_f32_16x16x32_bf16(af[fm], b1f[fn], acc1[fm][fn], 0, 0, 0);
          acc2[fm][fn] = __builtin_amdgcn_mfma_f32_16x16x32_bf16(af[fm], b2f[fn], acc2[fm][fn], 0, 0, 0);
        }
    }
    __syncthreads();
  }

  int hb = 0;
  #pragma unroll
  for (int j = 0; j < NE; j++) if (j < e) hb += cnt[j];
  #pragma unroll
  for (int fm = 0; fm < 4; fm++)
    #pragma unroll
    for (int fn = 0; fn < 2; fn++)
      #pragma unroll
      for (int r = 0; r < 4; r++) {
        int row = wm * 64 + fm * 16 + quad * 4 + r;   // C/D: col=lane&15, row=quad*4+reg
        if (mt * 128 + row < count) {
          float a = acc1[fm][fn][r];
          float v = acc2[fm][fn][r];
          float h = (a / (1.f + __expf(-a))) * v;
          int col = nt * 64 + wn * 32 + fn * 16 + m16;
          hbuf[(size_t)(hb + mt * 128 + row) * HID + col] = f2bf(h);
        }
      }
}

// y = hbuf @ W3t^T -> grouped ybuf (fp32, plain stores, no atomics).
// tile 128x128, K-step 64.
__global__ __launch_bounds__(256, 3) void gemm2_kernel(
    const unsigned short* __restrict__ hbuf,
    const unsigned short* __restrict__ w3t,
    const int* __restrict__ cnt,
    float* __restrict__ ybuf) {
  int e = blockIdx.z;
  int count = cnt[e];
  int mt = blockIdx.y;
  if (mt * 128 >= count) return;
  int nt = blockIdx.x;
  int hb = 0;
  #pragma unroll
  for (int j = 0; j < NE; j++) if (j < e) hb += cnt[j];

  __shared__ __align__(16) unsigned short As[128 * 64];
  __shared__ __align__(16) unsigned short Bs[128 * 64];

  int tid = threadIdx.x;
  int wid = tid >> 6, lane = tid & 63;
  int wm = wid >> 1, wn = wid & 1;
  int m16 = lane & 15, quad = lane >> 4;

  const unsigned short* W3e = w3t + (size_t)e * DIM * HID + (size_t)(nt * 128) * HID;

  const unsigned short *aptr[4], *bptr[4];
  #pragma unroll
  for (int i = 0; i < 4; i++) {
    int slot = wid * 256 + i * 64 + lane;
    int r = slot >> 3, c = slot & 7, g = c ^ (r & 7);
    int gr = mt * 128 + r;
    int rc = (gr < count) ? gr : (count - 1);
    aptr[i] = hbuf + (size_t)(hb + rc) * HID + g * 8;
    bptr[i] = W3e + (size_t)r * HID + g * 8;
  }

  f32x4 acc[4][4];
  f32x4 zz = {0.f, 0.f, 0.f, 0.f};
  #pragma unroll
  for (int i = 0; i < 4; i++)
    #pragma unroll
    for (int j = 0; j < 4; j++) acc[i][j] = zz;

  for (int k0 = 0; k0 < HID; k0 += 64) {
    #pragma unroll
    for (int i = 0; i < 4; i++) {
      gl2lds16(aptr[i] + k0, As + (wid * 256 + i * 64) * 8);
      gl2lds16(bptr[i] + k0, Bs + (wid * 256 + i * 64) * 8);
    }
    __syncthreads();
    #pragma unroll
    for (int ks = 0; ks < 2; ks++) {
      int ga = ks * 4 + quad;
      short8 af[4], bf[4];
      #pragma unroll
      for (int fm = 0; fm < 4; fm++) {
        int ra = wm * 64 + fm * 16 + m16;
        af[fm] = *(const short8*)(As + ra * 64 + (ga ^ (ra & 7)) * 8);
      }
      #pragma unroll
      for (int fn = 0; fn < 4; fn++) {
        int rb = wn * 64 + fn * 16 + m16;
        bf[fn] = *(const short8*)(Bs + rb * 64 + (ga ^ (rb & 7)) * 8);
      }
      #pragma unroll
      for (int fm = 0; fm < 4; fm++)
        #pragma unroll
        for (int fn = 0; fn < 4; fn++)
          acc[fm][fn] = __builtin_amdgcn_mfma_f32_16x16x32_bf16(af[fm], bf[fn], acc[fm][fn], 0, 0, 0);
    }
    __syncthreads();
  }

  #pragma unroll
  for (int fm = 0; fm < 4; fm++)
    #pragma unroll
    for (int fn = 0; fn < 4; fn++)
      #pragma unroll
      for (int r = 0; r < 4; r++) {
        int row = wm * 64 + fm * 16 + quad * 4 + r;
        if (mt * 128 + row < count) {
          int col = nt * 128 + wn * 64 + fn * 16 + m16;
          ybuf[(size_t)(hb + mt * 128 + row) * DIM + col] = acc[fm][fn][r];
        }
      }
}

// out[t] = p0 * ybuf[row0] + p1 * ybuf[row1]; fully coalesced, no pre-zero needed.
__global__ __launch_bounds__(256) void combine_kernel(
    const float* __restrict__ ybuf, const int* __restrict__ cnt,
    const int* __restrict__ slotpos, const float* __restrict__ eprob,
    float* __restrict__ out) {
  __shared__ int sbase[NE];
  if (threadIdx.x == 0) {
    int s = 0;
    #pragma unroll
    for (int e = 0; e < NE; e++) { sbase[e] = s; s += cnt[e]; }
  }
  __syncthreads();
  int t = blockIdx.x;
  int ps0 = slotpos[2 * t], ps1 = slotpos[2 * t + 1];
  int r0 = sbase[ps0 >> 16] + (ps0 & 0xffff);
  int r1 = sbase[ps1 >> 16] + (ps1 & 0xffff);
  float p0 = eprob[2 * t], p1 = eprob[2 * t + 1];
  int d = threadIdx.x * 4;
  float4 y0 = *(const float4*)(ybuf + (size_t)r0 * DIM + d);
  float4 y1 = *(const float4*)(ybuf + (size_t)r1 * DIM + d);
  float4 o;
  o.x = p0 * y0.x + p1 * y1.x;
  o.y = p0 * y0.y + p1 * y1.y;
  o.z = p0 * y0.z + p1 * y1.z;
  o.w = p0 * y0.w + p1 * y1.w;
  *(float4*)(out + (size_t)t * DIM + d) = o;
}

extern "C" void kernel_launch(void* const* d_in, const int* in_sizes, int n_in,
                              void* d_out, int out_size, void* d_ws, size_t ws_size,
                              hipStream_t stream) {
  const float* x  = (const float*)d_in[0];
  const float* Wg = (const float*)d_in[1];
  const float* W1 = (const float*)d_in[2];
  const float* W2 = (const float*)d_in[3];
  const float* W3 = (const float*)d_in[4];
  float* out = (float*)d_out;

  // workspace layout (~185 MB total); ybuf aliases w1t+w2t (dead before gemm2)
  char* ws = (char*)d_ws;
  size_t off = 0;
  int* cnt = (int*)(ws + off); off += 256;
  int* eidx = (int*)(ws + off); off += (size_t)NTOK * 4;
  float* eprob = (float*)(ws + off); off += (size_t)NTOK * 2 * 4;
  int* slotpos = (int*)(ws + off); off += (size_t)NTOK * 2 * 4;
  int* tok_list = (int*)(ws + off); off += (size_t)NE * NTOK * 4;
  unsigned short* xb  = (unsigned short*)(ws + off); off += (size_t)NTOK * DIM * 2;
  unsigned short* w1t = (unsigned short*)(ws + off); off += (size_t)NE * DIM * HID * 2;
  unsigned short* w2t = (unsigned short*)(ws + off); off += (size_t)NE * DIM * HID * 2;
  unsigned short* w3t = (unsigned short*)(ws + off); off += (size_t)NE * DIM * HID * 2;
  unsigned short* hbuf = (unsigned short*)(ws + off); off += (size_t)NTOK * 2 * HID * 2;
  float* ybuf = (float*)w1t;   // 16384*1024*4 B == |w1t|+|w2t| exactly

  gate_kernel<<<NTOK / 4, 256, 0, stream>>>(x, Wg, xb, eidx, eprob, cnt);
  transpose_cast_kernel<<<dim3(HID / 64, DIM / 64, NE), 256, 0, stream>>>(W1, w1t, DIM, HID);
  transpose_cast_kernel<<<dim3(HID / 64, DIM / 64, NE), 256, 0, stream>>>(W2, w2t, DIM, HID);
  transpose_cast_kernel<<<dim3(DIM / 64, HID / 64, NE), 256, 0, stream>>>(W3, w3t, HID, DIM);
  route_kernel<<<NTOK / 512, 512, 0, stream>>>(eidx, cnt, tok_list, slotpos);
  gemm1_kernel<<<dim3(HID / 64, NTOK / 128, NE), 256, 0, stream>>>(xb, w1t, w2t, cnt, tok_list, hbuf);
  gemm2_kernel<<<dim3(DIM / 128, NTOK / 128, NE), 256, 0, stream>>>(hbuf, w3t, cnt, ybuf);
  combine_kernel<<<NTOK, 256, 0, stream>>>(ybuf, cnt, slotpos, eprob, out);
}

// Round 5
// 514.983 us; speedup vs baseline: 1.7473x; 1.0236x over previous
//
#include <hip/hip_runtime.h>
#include <stdint.h>
#include <math.h>

#define NTOK  8192
#define DIM   1024
#define HID   2048
#define NE    8

typedef __attribute__((ext_vector_type(8))) short short8;
typedef __attribute__((ext_vector_type(4))) float f32x4;

__device__ __forceinline__ unsigned short f2bf(float f) {
  union { float f; unsigned u; } a; a.f = f;
  unsigned u = a.u;
  u += 0x7fffu + ((u >> 16) & 1u);   // RNE
  return (unsigned short)(u >> 16);
}

__device__ __forceinline__ float bf2f(unsigned short s) {
  union { unsigned u; float f; } a; a.u = ((unsigned)s) << 16;
  return a.f;
}

// async global->LDS, 16B per lane. lds dest = wave-uniform base + lane*16.
__device__ __forceinline__ void gl2lds16(const unsigned short* g, unsigned short* l) {
  __builtin_amdgcn_global_load_lds(
      (const __attribute__((address_space(1))) unsigned int*)g,
      (__attribute__((address_space(3))) unsigned int*)l,
      16, 0, 0);
}

// All three weight transposes in one launch. fp32 [e][R][C] -> bf16 [e][C][R].
// b < 4096: W1; b < 8192: W2; else W3.
__global__ __launch_bounds__(256) void transpose_all_kernel(
    const float* __restrict__ W1, const float* __restrict__ W2, const float* __restrict__ W3,
    unsigned short* __restrict__ w1t, unsigned short* __restrict__ w2t,
    unsigned short* __restrict__ w3t) {
  __shared__ unsigned short tileT[64][72];
  int b = blockIdx.x;
  int which = b >> 12;          // 0,1,2
  int rem = b & 4095;
  const float* in;
  unsigned short* out;
  int R, C, bx, by, e;
  if (which < 2) {
    R = DIM; C = HID;
    bx = rem & 31; by = (rem >> 5) & 15; e = rem >> 9;
    in = (which == 0 ? W1 : W2);
    out = (which == 0 ? w1t : w2t);
  } else {
    R = HID; C = DIM;
    bx = rem & 15; by = (rem >> 4) & 31; e = rem >> 9;
    in = W3; out = w3t;
  }
  const float* ine = in + (size_t)e * R * C + (size_t)(by * 64) * C + bx * 64;
  unsigned short* oute = out + (size_t)e * R * C + (size_t)(bx * 64) * R + by * 64;
  int t = threadIdx.x;
  #pragma unroll
  for (int i = 0; i < 4; i++) {
    int idx = t + i * 256;
    int r = idx >> 4, c = (idx & 15) * 4;
    float4 v = *(const float4*)(ine + (size_t)r * C + c);
    tileT[c + 0][r] = f2bf(v.x);
    tileT[c + 1][r] = f2bf(v.y);
    tileT[c + 2][r] = f2bf(v.z);
    tileT[c + 3][r] = f2bf(v.w);
  }
  __syncthreads();
  #pragma unroll
  for (int i = 0; i < 2; i++) {
    int idx = t + i * 256;
    int rr = idx >> 3, cc = (idx & 7) * 8;
    *(uint4*)(oute + (size_t)rr * R + cc) = *(const uint4*)(&tileT[rr][cc]);
  }
}

// one wave per token: gate = x @ Wg, top-2 + softmax -> packed idx + probs.
// Fuses x -> bf16 cast. Block 0 zeroes cnt (race-free: route runs after).
__global__ __launch_bounds__(256) void gate_kernel(
    const float* __restrict__ x, const float* __restrict__ Wg,
    unsigned short* __restrict__ xb,
    int* __restrict__ eidx, float* __restrict__ eprob, int* __restrict__ cnt) {
  if (blockIdx.x == 0 && threadIdx.x < NE) cnt[threadIdx.x] = 0;
  int wid = threadIdx.x >> 6;
  int lane = threadIdx.x & 63;
  int t = blockIdx.x * 4 + wid;
  const float* xr = x + (size_t)t * DIM;
  unsigned short* xbr = xb + (size_t)t * DIM;
  float acc[NE];
  #pragma unroll
  for (int e = 0; e < NE; e++) acc[e] = 0.f;
  #pragma unroll
  for (int it = 0; it < DIM / 64; it++) {
    int d = it * 64 + lane;
    float xv = xr[d];
    xbr[d] = f2bf(xv);
    const float4* wr = (const float4*)(Wg + d * NE);
    float4 w0 = wr[0], w1 = wr[1];
    acc[0] += xv * w0.x; acc[1] += xv * w0.y; acc[2] += xv * w0.z; acc[3] += xv * w0.w;
    acc[4] += xv * w1.x; acc[5] += xv * w1.y; acc[6] += xv * w1.z; acc[7] += xv * w1.w;
  }
  #pragma unroll
  for (int e = 0; e < NE; e++) {
    float v = acc[e];
    #pragma unroll
    for (int off = 32; off > 0; off >>= 1) v += __shfl_xor(v, off);
    acc[e] = v;
  }
  if (lane == 0) {
    int i0 = 0; float v0 = acc[0];
    #pragma unroll
    for (int e = 1; e < NE; e++) if (acc[e] > v0) { v0 = acc[e]; i0 = e; }
    int i1 = -1; float v1 = -3.4e38f;
    #pragma unroll
    for (int e = 0; e < NE; e++) if (e != i0 && acc[e] > v1) { v1 = acc[e]; i1 = e; }
    float e1 = expf(v1 - v0);
    float p0 = 1.f / (1.f + e1);
    float p1 = e1 / (1.f + e1);
    eidx[t] = i0 | (i1 << 16);
    eprob[2 * t] = p0;
    eprob[2 * t + 1] = p1;
  }
}

// per-block LDS histogram, one global atomic per (block, expert), then scatter.
__global__ __launch_bounds__(512) void route_kernel(
    const int* __restrict__ eidx,
    int* __restrict__ cnt, int* __restrict__ tok_list, int* __restrict__ slotpos) {
  __shared__ int lhist[NE];
  __shared__ int gbase[NE];
  int tid = threadIdx.x;
  if (tid < NE) lhist[tid] = 0;
  __syncthreads();
  int t = blockIdx.x * 512 + tid;
  int pk = eidx[t];
  int i0 = pk & 0xffff, i1 = pk >> 16;
  int l0 = atomicAdd(&lhist[i0], 1);
  int l1 = atomicAdd(&lhist[i1], 1);
  __syncthreads();
  if (tid < NE) gbase[tid] = atomicAdd(&cnt[tid], lhist[tid]);
  __syncthreads();
  int s0 = gbase[i0] + l0;
  int s1 = gbase[i1] + l1;
  tok_list[i0 * NTOK + s0] = t;
  tok_list[i1 * NTOK + s1] = t;
  slotpos[2 * t] = (i0 << 16) | s0;
  slotpos[2 * t + 1] = (i1 << 16) | s1;
}

// grouped dual GEMM: a = A@W1t^T, v = A@W2t^T; h = swish(a)*v -> hbuf (bf16)
// tile M=128 x N=64(x2), K-step 64. XOR-swizzled LDS, async staging.
__global__ __launch_bounds__(256, 3) void gemm1_kernel(
    const unsigned short* __restrict__ xb,
    const unsigned short* __restrict__ w1t,
    const unsigned short* __restrict__ w2t,
    const int* __restrict__ cnt,
    const int* __restrict__ tok_list,
    unsigned short* __restrict__ hbuf) {
  int e = blockIdx.z;
  int count = cnt[e];
  int mt = blockIdx.y;
  if (mt * 128 >= count) return;
  int nt = blockIdx.x;

  __shared__ __align__(16) unsigned short As[128 * 64];
  __shared__ __align__(16) unsigned short Bs1[64 * 64];
  __shared__ __align__(16) unsigned short Bs2[64 * 64];
  __shared__ int toks[128];

  int tid = threadIdx.x;
  if (tid < 128) {
    int r = mt * 128 + tid;
    toks[tid] = tok_list[e * NTOK + (r < count ? r : 0)];
  }
  __syncthreads();

  int wid = tid >> 6, lane = tid & 63;
  int wm = wid >> 1, wn = wid & 1;
  int m16 = lane & 15, quad = lane >> 4;

  const unsigned short* W1e = w1t + (size_t)e * HID * DIM + (size_t)(nt * 64) * DIM;
  const unsigned short* W2e = w2t + (size_t)e * HID * DIM + (size_t)(nt * 64) * DIM;

  const unsigned short* aptr[4];
  #pragma unroll
  for (int i = 0; i < 4; i++) {
    int slot = wid * 256 + i * 64 + lane;
    int r = slot >> 3, c = slot & 7, g = c ^ (r & 7);
    aptr[i] = xb + (size_t)toks[r] * DIM + g * 8;
  }
  const unsigned short *b1p[2], *b2p[2];
  #pragma unroll
  for (int i = 0; i < 2; i++) {
    int slot = wid * 128 + i * 64 + lane;
    int r = slot >> 3, c = slot & 7, g = c ^ (r & 7);
    b1p[i] = W1e + (size_t)r * DIM + g * 8;
    b2p[i] = W2e + (size_t)r * DIM + g * 8;
  }

  f32x4 acc1[4][2], acc2[4][2];
  f32x4 zz = {0.f, 0.f, 0.f, 0.f};
  #pragma unroll
  for (int i = 0; i < 4; i++)
    #pragma unroll
    for (int j = 0; j < 2; j++) { acc1[i][j] = zz; acc2[i][j] = zz; }

  for (int k0 = 0; k0 < DIM; k0 += 64) {
    #pragma unroll
    for (int i = 0; i < 4; i++)
      gl2lds16(aptr[i] + k0, As + (wid * 256 + i * 64) * 8);
    #pragma unroll
    for (int i = 0; i < 2; i++) {
      gl2lds16(b1p[i] + k0, Bs1 + (wid * 128 + i * 64) * 8);
      gl2lds16(b2p[i] + k0, Bs2 + (wid * 128 + i * 64) * 8);
    }
    __syncthreads();
    #pragma unroll
    for (int ks = 0; ks < 2; ks++) {
      int ga = ks * 4 + quad;
      short8 af[4], b1f[2], b2f[2];
      #pragma unroll
      for (int fm = 0; fm < 4; fm++) {
        int ra = wm * 64 + fm * 16 + m16;
        af[fm] = *(const short8*)(As + ra * 64 + (ga ^ (ra & 7)) * 8);
      }
      #pragma unroll
      for (int fn = 0; fn < 2; fn++) {
        int rb = wn * 32 + fn * 16 + m16;
        b1f[fn] = *(const short8*)(Bs1 + rb * 64 + (ga ^ (rb & 7)) * 8);
        b2f[fn] = *(const short8*)(Bs2 + rb * 64 + (ga ^ (rb & 7)) * 8);
      }
      #pragma unroll
      for (int fm = 0; fm < 4; fm++)
        #pragma unroll
        for (int fn = 0; fn < 2; fn++) {
          acc1[fm][fn] = __builtin_amdgcn_mfma_f32_16x16x32_bf16(af[fm], b1f[fn], acc1[fm][fn], 0, 0, 0);
          acc2[fm][fn] = __builtin_amdgcn_mfma_f32_16x16x32_bf16(af[fm], b2f[fn], acc2[fm][fn], 0, 0, 0);
        }
    }
    __syncthreads();
  }

  int hb = 0;
  #pragma unroll
  for (int j = 0; j < NE; j++) if (j < e) hb += cnt[j];
  #pragma unroll
  for (int fm = 0; fm < 4; fm++)
    #pragma unroll
    for (int fn = 0; fn < 2; fn++)
      #pragma unroll
      for (int r = 0; r < 4; r++) {
        int row = wm * 64 + fm * 16 + quad * 4 + r;   // C/D: col=lane&15, row=quad*4+reg
        if (mt * 128 + row < count) {
          float a = acc1[fm][fn][r];
          float v = acc2[fm][fn][r];
          float h = (a / (1.f + __expf(-a))) * v;
          int col = nt * 64 + wn * 32 + fn * 16 + m16;
          hbuf[(size_t)(hb + mt * 128 + row) * HID + col] = f2bf(h);
        }
      }
}

// y = hbuf @ W3t^T -> grouped ybuf (bf16, plain stores).
// tile M=64 x N=128, K-step 64: 2x active blocks vs M=128 (tail packing),
// light LDS (24 KB) + light VGPR -> 4 blocks/CU.
__global__ __launch_bounds__(256, 4) void gemm2_kernel(
    const unsigned short* __restrict__ hbuf,
    const unsigned short* __restrict__ w3t,
    const int* __restrict__ cnt,
    unsigned short* __restrict__ ybuf) {
  int e = blockIdx.z;
  int count = cnt[e];
  int mt = blockIdx.y;
  if (mt * 64 >= count) return;
  int nt = blockIdx.x;
  int hb = 0;
  #pragma unroll
  for (int j = 0; j < NE; j++) if (j < e) hb += cnt[j];

  __shared__ __align__(16) unsigned short As[64 * 64];
  __shared__ __align__(16) unsigned short Bs[128 * 64];

  int tid = threadIdx.x;
  int wid = tid >> 6, lane = tid & 63;   // wid = wn in 0..3
  int m16 = lane & 15, quad = lane >> 4;

  const unsigned short* W3e = w3t + (size_t)e * DIM * HID + (size_t)(nt * 128) * HID;

  const unsigned short *aptr[2], *bptr[4];
  #pragma unroll
  for (int i = 0; i < 2; i++) {
    int slot = tid + 256 * i;
    int r = slot >> 3, c = slot & 7, g = c ^ (r & 7);
    int gr = mt * 64 + r;
    int rc = (gr < count) ? gr : (count - 1);
    aptr[i] = hbuf + (size_t)(hb + rc) * HID + g * 8;
  }
  #pragma unroll
  for (int i = 0; i < 4; i++) {
    int slot = tid + 256 * i;
    int r = slot >> 3, c = slot & 7, g = c ^ (r & 7);
    bptr[i] = W3e + (size_t)r * HID + g * 8;
  }

  f32x4 acc[4][2];
  f32x4 zz = {0.f, 0.f, 0.f, 0.f};
  #pragma unroll
  for (int i = 0; i < 4; i++)
    #pragma unroll
    for (int j = 0; j < 2; j++) acc[i][j] = zz;

  for (int k0 = 0; k0 < HID; k0 += 64) {
    #pragma unroll
    for (int i = 0; i < 2; i++)
      gl2lds16(aptr[i] + k0, As + (tid >> 6) * 0 + ((size_t)(256 * i) + (tid & ~63) + (tid & 63)) * 8);
    #pragma unroll
    for (int i = 0; i < 4; i++)
      gl2lds16(bptr[i] + k0, Bs + ((size_t)(256 * i) + tid) * 8);
    __syncthreads();
    #pragma unroll
    for (int ks = 0; ks < 2; ks++) {
      int ga = ks * 4 + quad;
      short8 af[4], bf[2];
      #pragma unroll
      for (int fm = 0; fm < 4; fm++) {
        int ra = fm * 16 + m16;
        af[fm] = *(const short8*)(As + ra * 64 + (ga ^ (ra & 7)) * 8);
      }
      #pragma unroll
      for (int fn = 0; fn < 2; fn++) {
        int rb = wid * 32 + fn * 16 + m16;
        bf[fn] = *(const short8*)(Bs + rb * 64 + (ga ^ (rb & 7)) * 8);
      }
      #pragma unroll
      for (int fm = 0; fm < 4; fm++)
        #pragma unroll
        for (int fn = 0; fn < 2; fn++)
          acc[fm][fn] = __builtin_amdgcn_mfma_f32_16x16x32_bf16(af[fm], bf[fn], acc[fm][fn], 0, 0, 0);
    }
    __syncthreads();
  }

  #pragma unroll
  for (int fm = 0; fm < 4; fm++)
    #pragma unroll
    for (int fn = 0; fn < 2; fn++)
      #pragma unroll
      for (int r = 0; r < 4; r++) {
        int row = fm * 16 + quad * 4 + r;
        if (mt * 64 + row < count) {
          int col = nt * 128 + wid * 32 + fn * 16 + m16;
          ybuf[(size_t)(hb + mt * 64 + row) * DIM + col] = f2bf(acc[fm][fn][r]);
        }
      }
}

// out[t] = p0 * ybuf[row0] + p1 * ybuf[row1]; 8 tokens per block, bf16 gather.
__global__ __launch_bounds__(256) void combine_kernel(
    const unsigned short* __restrict__ ybuf, const int* __restrict__ cnt,
    const int* __restrict__ slotpos, const float* __restrict__ eprob,
    float* __restrict__ out) {
  __shared__ int sbase[NE];
  if (threadIdx.x == 0) {
    int s = 0;
    #pragma unroll
    for (int e = 0; e < NE; e++) { sbase[e] = s; s += cnt[e]; }
  }
  __syncthreads();
  int d = threadIdx.x * 4;
  #pragma unroll
  for (int i = 0; i < 8; i++) {
    int t = blockIdx.x * 8 + i;
    int ps0 = slotpos[2 * t], ps1 = slotpos[2 * t + 1];
    int r0 = sbase[ps0 >> 16] + (ps0 & 0xffff);
    int r1 = sbase[ps1 >> 16] + (ps1 & 0xffff);
    float p0 = eprob[2 * t], p1 = eprob[2 * t + 1];
    ushort4 y0 = *(const ushort4*)(ybuf + (size_t)r0 * DIM + d);
    ushort4 y1 = *(const ushort4*)(ybuf + (size_t)r1 * DIM + d);
    float4 o;
    o.x = p0 * bf2f(y0.x) + p1 * bf2f(y1.x);
    o.y = p0 * bf2f(y0.y) + p1 * bf2f(y1.y);
    o.z = p0 * bf2f(y0.z) + p1 * bf2f(y1.z);
    o.w = p0 * bf2f(y0.w) + p1 * bf2f(y1.w);
    *(float4*)(out + (size_t)t * DIM + d) = o;
  }
}

extern "C" void kernel_launch(void* const* d_in, const int* in_sizes, int n_in,
                              void* d_out, int out_size, void* d_ws, size_t ws_size,
                              hipStream_t stream) {
  const float* x  = (const float*)d_in[0];
  const float* Wg = (const float*)d_in[1];
  const float* W1 = (const float*)d_in[2];
  const float* W2 = (const float*)d_in[3];
  const float* W3 = (const float*)d_in[4];
  float* out = (float*)d_out;

  // workspace layout (~185 MB total); ybuf (bf16, 33.5 MB) aliases w1t (dead by gemm2)
  char* ws = (char*)d_ws;
  size_t off = 0;
  int* cnt = (int*)(ws + off); off += 256;
  int* eidx = (int*)(ws + off); off += (size_t)NTOK * 4;
  float* eprob = (float*)(ws + off); off += (size_t)NTOK * 2 * 4;
  int* slotpos = (int*)(ws + off); off += (size_t)NTOK * 2 * 4;
  int* tok_list = (int*)(ws + off); off += (size_t)NE * NTOK * 4;
  unsigned short* xb  = (unsigned short*)(ws + off); off += (size_t)NTOK * DIM * 2;
  unsigned short* w1t = (unsigned short*)(ws + off); off += (size_t)NE * DIM * HID * 2;
  unsigned short* w2t = (unsigned short*)(ws + off); off += (size_t)NE * DIM * HID * 2;
  unsigned short* w3t = (unsigned short*)(ws + off); off += (size_t)NE * DIM * HID * 2;
  unsigned short* hbuf = (unsigned short*)(ws + off); off += (size_t)NTOK * 2 * HID * 2;
  unsigned short* ybuf = w1t;   // 16384*1024*2 B = 33.5 MB fits in |w1t| (67 MB)

  gate_kernel<<<NTOK / 4, 256, 0, stream>>>(x, Wg, xb, eidx, eprob, cnt);
  transpose_all_kernel<<<3 * 4096, 256, 0, stream>>>(W1, W2, W3, w1t, w2t, w3t);
  route_kernel<<<NTOK / 512, 512, 0, stream>>>(eidx, cnt, tok_list, slotpos);
  gemm1_kernel<<<dim3(HID / 64, NTOK / 128, NE), 256, 0, stream>>>(xb, w1t, w2t, cnt, tok_list, hbuf);
  gemm2_kernel<<<dim3(DIM / 128, NTOK / 64, NE), 256, 0, stream>>>(hbuf, w3t, cnt, ybuf);
  combine_kernel<<<NTOK / 8, 256, 0, stream>>>(ybuf, cnt, slotpos, eprob, out);
}